// Round 6
// baseline (1067.850 us; speedup 1.0000x reference)
//
#include <hip/hip_runtime.h>
#include <hip/hip_bf16.h>

#define B_      2
#define S_      1024
#define HID     4096
#define NH      32
#define NKV     8
#define D_      128
#define G_      4
#define WINDOW  512
#define QKV_OUT 6144      // (NH + 2*NKV) * D
#define M_TOT   2048      // B * S
#define CH      32        // kv chunk length in attention
#define VSTR    40        // transposed-V row stride (80 B: 16B-aligned frags, 2-way banks)

typedef __bf16 bf16x8 __attribute__((ext_vector_type(8)));
typedef float  f32x4  __attribute__((ext_vector_type(4)));
typedef unsigned short u16x8 __attribute__((ext_vector_type(8)));

#define AS1 __attribute__((address_space(1)))
#define AS3 __attribute__((address_space(3)))

static __device__ __forceinline__ float bf2f(unsigned short u) {
    union { unsigned int i; float f; } v; v.i = ((unsigned int)u) << 16; return v.f;
}
static __device__ __forceinline__ unsigned short f2bf(float f) {
    union { float f; unsigned int i; } v; v.f = f;
    unsigned int x = v.i;
    return (unsigned short)((x + 0x7fffu + ((x >> 16) & 1u)) >> 16);
}
static __device__ __forceinline__ void gl2lds16(const void* g, void* l) {
    __builtin_amdgcn_global_load_lds((const AS1 void*)g, (AS3 void*)l, 16, 0, 0);
}

// ---------------- fp32 -> bf16 bulk conversion (RTNE) ----------------
__global__ __launch_bounds__(256)
void conv_f32_bf16(const float* __restrict__ src, unsigned short* __restrict__ dst, int n8)
{
    int i = blockIdx.x * 256 + threadIdx.x;
    if (i >= n8) return;
    const float* p = src + (size_t)i * 8;
    float4 f0 = *(const float4*)p;
    float4 f1 = *(const float4*)(p + 4);
    u16x8 h;
    h[0]=f2bf(f0.x); h[1]=f2bf(f0.y); h[2]=f2bf(f0.z); h[3]=f2bf(f0.w);
    h[4]=f2bf(f1.x); h[5]=f2bf(f1.y); h[6]=f2bf(f1.z); h[7]=f2bf(f1.w);
    *(u16x8*)&dst[(size_t)i * 8] = h;
}

// ================= 256x256 4-phase pipelined GEMM =================
// C[M][N] = A[M][K]*Bw[N][K]^T + bias.  BK=64, 512 thr = 8 waves (2M x 4N),
// per-wave C = 128x64 (acc[8][4]).  LDS 128 KiB double-buffered.
// 3-bit LDS swizzle (round-2, verified 0 bank conflicts): phys 16B-slot =
// logical slot ^ (row&7), both-sides (linear gl2lds dest + inverse per-lane
// global source + XOR'd ds_read).
// Round-5 FAILED (absmax 0.748): rdBoundary(i+1) before P4's MFMA overwrote
// the bC REGISTERS that MFMA(6,7) still needed with tile-i values -> compiler
// drained the new loads and fed tile-(i+1) B with tile-i A.  Round-6 fix:
// double-buffer B frags (bCA/bCB, +32 VGPR; occupancy is LDS-bound at
// 1 block/CU so registers are free) and alternate sets via 2x-unrolled main
// loop (static indexing only, rule #20).  aP needs no second set: dead at P4
// (consumed in P3; in-order issue covers the WAR).
// P4: vmcnt(4) -> bar -> stA(i+2,0) -> RDBOUND(i+1 -> BNEW,aP) -> lgkm(12)
//     [drains only aQ, in-order ds FIFO] -> MFMA(6,7,aQ,BOLD) -> bar
// so the 12-read boundary burst services UNDER the 128-MFMA cluster.
// Hazard proofs (as round-5, all re-checked):
//   stB(i+2,*)@P2/P3 vs boundary-B(i) reads: drained P1 lgkm(4) + P1-end bar.
//   stA(i+2,0)@P4 vs aQ(2,3) reads: P2 lgkm(4) precedes P4-mid bar (prog order).
//   stA(i+1,1)@P1 vs aP45/aQ67 of tile i-1: P3/P4 lgkm + P4-end bar.
//   RDBOUND(i+1) reads: all 8 stage loads of tile i+1 retired by per-wave
//   vmcnt(4) + P4-mid bar.
// vmcnt ledger (steady): enter tile with 6 = [B(i+1)x4, A(i+1,0)x2];
//   P1 +2, P2 +2, P3 +2 = 12; P4 vmcnt(4) retires tile i+1's 8 (FIFO-oldest);
//   +2 (stA(i+2,0)) = 6 carried.  Never 0 mid-loop.  i=nkt-2 -> vmcnt(0);
//   i=nkt-1 -> plain lgkm(0)+MFMA.
// lgkm ledger (ds-only FIFO; gl2lds counts vmcnt): P1 wait(4): 12 boundary +
//   4 aQ -> drains boundary.  P2/P3 wait(4): 4 old + 4 new -> drains old.
//   P4 wait(12): 4 aQ + 12 boundary -> drains aQ; boundary stays in flight
//   across P4-end bar, drained at next P1 wait(4).
#define MFMA_CL(MT0, MT1, AR, BS)                                                      \
    __builtin_amdgcn_s_setprio(1);                                                     \
    _Pragma("unroll")                                                                  \
    for (int ks = 0; ks < 2; ++ks) {                                                   \
        _Pragma("unroll")                                                              \
        for (int nt = 0; nt < 4; ++nt) {                                               \
            acc[MT0][nt] = __builtin_amdgcn_mfma_f32_16x16x32_bf16(AR[0][ks], BS[nt][ks], acc[MT0][nt], 0, 0, 0); \
            acc[MT1][nt] = __builtin_amdgcn_mfma_f32_16x16x32_bf16(AR[1][ks], BS[nt][ks], acc[MT1][nt], 0, 0, 0); \
        }                                                                              \
    }                                                                                  \
    __builtin_amdgcn_s_setprio(0);

#define SCHED __builtin_amdgcn_sched_barrier(0)
#define WAITLGKM(N) do { asm volatile("s_waitcnt lgkmcnt(" #N ")" ::: "memory"); SCHED; } while (0)
#define BARRIER do { SCHED; __builtin_amdgcn_s_barrier(); SCHED; } while (0)

#define RDBOUND(T, BS) do {                                                            \
    const int bufo_ = ((T) & 1) << 14;                                                 \
    _Pragma("unroll")                                                                  \
    for (int nt = 0; nt < 4; ++nt)                                                     \
        _Pragma("unroll")                                                              \
        for (int ks = 0; ks < 2; ++ks) BS[nt][ks] = rdB(bufo_, nt, ks);                \
    _Pragma("unroll")                                                                  \
    for (int ks = 0; ks < 2; ++ks) { aP[0][ks] = rdA(bufo_, 0, ks); aP[1][ks] = rdA(bufo_, 1, ks); } \
} while (0)

#define TILE_BODY(II, BOLD, BNEW) do {                                                 \
    const int i_ = (II);                                                               \
    const int bufo = (i_ & 1) << 14;                                                   \
    /* P1: MFMA mt0,1 (aP,BOLD); prefetch mt2,3 -> aQ */                               \
    if (i_ + 1 < nkt) stA(i_ + 1, 1);                                                  \
    _Pragma("unroll")                                                                  \
    for (int ks = 0; ks < 2; ++ks) { aQ[0][ks] = rdA(bufo, 2, ks); aQ[1][ks] = rdA(bufo, 3, ks); } \
    SCHED; WAITLGKM(4);                                                                \
    MFMA_CL(0, 1, aP, BOLD)                                                            \
    BARRIER;                                                                           \
    /* P2: MFMA mt2,3 (aQ,BOLD); prefetch mt4,5 -> aP (no end barrier) */              \
    if (i_ + 2 < nkt) stB(i_ + 2, 0);                                                  \
    _Pragma("unroll")                                                                  \
    for (int ks = 0; ks < 2; ++ks) { aP[0][ks] = rdA(bufo, 4, ks); aP[1][ks] = rdA(bufo, 5, ks); } \
    SCHED; WAITLGKM(4);                                                                \
    MFMA_CL(2, 3, aQ, BOLD)                                                            \
    /* P3: MFMA mt4,5 (aP,BOLD); prefetch mt6,7 -> aQ (no end barrier) */              \
    if (i_ + 2 < nkt) stB(i_ + 2, 1);                                                  \
    _Pragma("unroll")                                                                  \
    for (int ks = 0; ks < 2; ++ks) { aQ[0][ks] = rdA(bufo, 6, ks); aQ[1][ks] = rdA(bufo, 7, ks); } \
    SCHED; WAITLGKM(4);                                                                \
    MFMA_CL(4, 5, aP, BOLD)                                                            \
    SCHED;                                                                             \
    /* P4: vmcnt + bar + stage + boundary(i+1 -> BNEW), MFMA mt6,7 under it */         \
    if (i_ + 1 < nkt) {                                                                \
        if (i_ + 2 < nkt) { asm volatile("s_waitcnt vmcnt(4)" ::: "memory"); }         \
        else              { asm volatile("s_waitcnt vmcnt(0)" ::: "memory"); }         \
        BARRIER;                                                                       \
        if (i_ + 2 < nkt) stA(i_ + 2, 0);                                              \
        RDBOUND(i_ + 1, BNEW);                                                         \
        SCHED; WAITLGKM(12);                                                           \
        MFMA_CL(6, 7, aQ, BOLD)                                                        \
        BARRIER;                                                                       \
    } else {                                                                           \
        WAITLGKM(0);                                                                   \
        MFMA_CL(6, 7, aQ, BOLD)                                                        \
    }                                                                                  \
} while (0)

template<bool C_BF16>
__global__ __launch_bounds__(512, 2)
void gemm256_8ph(const unsigned short* __restrict__ A,
                 const unsigned short* __restrict__ Bw,
                 const float* __restrict__ bias,
                 void* __restrict__ Cv,
                 int M, int N, int K)
{
    __shared__ __attribute__((aligned(1024))) unsigned short lds[65536];  // 128 KiB

    const int tid  = threadIdx.x;
    const int lane = tid & 63;
    const int w    = tid >> 6;        // 0..7
    const int m_   = w >> 2;          // 0..1  (M half)
    const int n_   = w & 3;           // 0..3  (N quarter)
    const int lm   = lane & 15, quad = lane >> 4;
    const int m0   = blockIdx.y * 256, n0 = blockIdx.x * 256;
    const int nkt  = K >> 6;          // BK=64 tiles (requires nkt >= 4, even)

    // inverse-swizzled global source: lane l fills linear LDS chunk l
    // = phys (row l>>3, slot l&7), which holds logical (row l>>3, slot (l&7)^(l>>3))
    const int srow = lane >> 3;                  // 0..7 row within 8-row instr
    const int scol = ((lane & 7) ^ srow) * 8;    // elem col within BK=64

    const int arow0 = m0 + m_ * 128 + n_ * 16;   // staged A rows n_*16..+15
    const int arow1 = arow0 + 64;                // staged A rows 64+n_*16..+15
    const int brow  = n0 + w * 32;               // staged B rows w*32..+31

    const int ldsAr = m_ * 8192;                            // A read base (own half)
    const int ldsA0 = ldsAr + n_ * 1024;                    // A stage rp0
    const int ldsA1 = ldsA0 + 4096;                         // A stage rp1
    const int ldsBs = 32768 + m_ * 8192 + n_ * 2048;        // B stage base
    const int ldsBr = 32768 + (n_ >> 1) * 8192 + (n_ & 1) * 4096;  // B read base

    f32x4 acc[8][4] = {};
    bf16x8 bCA[4][2], bCB[4][2];   // B frag double-buffer (tile parity)
    bf16x8 aP[2][2], aQ[2][2];     // A frag ping-pong (one phase ahead)

    auto stA = [&](int T, int rp) {
        const int k0   = T << 6;
        const int bufo = (T & 1) << 14;
        const int rb   = (rp ? arow1 : arow0) + srow;
        const int lb   = (rp ? ldsA1 : ldsA0) + bufo + lane * 8;
        gl2lds16(&A[(size_t)rb * K + k0 + scol],       &lds[lb]);
        gl2lds16(&A[(size_t)(rb + 8) * K + k0 + scol], &lds[lb + 512]);
    };
    auto stB = [&](int T, int pr) {
        const int k0   = T << 6;
        const int bufo = (T & 1) << 14;
        const int rb   = brow + pr * 16 + srow;
        const int lb   = ldsBs + pr * 1024 + bufo + lane * 8;
        gl2lds16(&Bw[(size_t)rb * K + k0 + scol],       &lds[lb]);
        gl2lds16(&Bw[(size_t)(rb + 8) * K + k0 + scol], &lds[lb + 512]);
    };
    auto rdA = [&](int bufo, int mt, int ks) -> bf16x8 {
        int e = (mt * 16 + lm) * 64 + ks * 32 + quad * 8;
        e ^= ((e >> 6) & 7) << 3;                 // slot ^= row&7 (conflict-free)
        return *(const bf16x8*)&lds[bufo + ldsAr + e];
    };
    auto rdB = [&](int bufo, int nt, int ks) -> bf16x8 {
        int e = (nt * 16 + lm) * 64 + ks * 32 + quad * 8;
        e ^= ((e >> 6) & 7) << 3;                 // base offsets 4096-mult: bits 6-8 clean
        return *(const bf16x8*)&lds[bufo + ldsBr + e];
    };

    // prologue: tile0 full (8 loads) + tile1 first-6; drain tile0, keep 6 in flight
    stB(0, 0); stB(0, 1); stA(0, 0); stA(0, 1);
    stB(1, 0); stB(1, 1); stA(1, 0);
    asm volatile("s_waitcnt vmcnt(6)" ::: "memory");
    BARRIER;
    RDBOUND(0, bCA);
    SCHED;

    #pragma unroll 1
    for (int ii = 0; ii < nkt; ii += 2) {
        TILE_BODY(ii,     bCA, bCB);
        TILE_BODY(ii + 1, bCB, bCA);
    }

    #pragma unroll
    for (int nt = 0; nt < 4; ++nt) {
        const int col = n0 + n_ * 64 + nt * 16 + lm;
        const float bv = bias[col];
        #pragma unroll
        for (int mt = 0; mt < 8; ++mt) {
            const int rowb = m0 + m_ * 128 + mt * 16 + quad * 4;
            #pragma unroll
            for (int r = 0; r < 4; ++r) {
                const float val = acc[mt][nt][r] + bv;
                if (C_BF16)
                    ((unsigned short*)Cv)[(size_t)(rowb + r) * N + col] = f2bf(val);
                else
                    ((float*)Cv)[(size_t)(rowb + r) * N + col] = val;
            }
        }
    }
}

// ---------------- fast GEMM: bf16 A/B, global_load_lds staging (m97 structure) ----------------
// Kept for the O-projection (M=2048,N=4096): 256^2 grid would be 128 blocks (half
// the CUs idle) -- wash vs this kernel's 512-block 128^2 tiling. Internal control.
template<bool C_BF16>
__global__ __launch_bounds__(256)
void gemm_bf16_bt(const unsigned short* __restrict__ A,
                  const unsigned short* __restrict__ Bw,
                  const float* __restrict__ bias,
                  void* __restrict__ Cv,
                  int M, int N, int K)
{
    __shared__ unsigned short As[128 * 32];   // unpadded: required by global_load_lds lane order
    __shared__ unsigned short Bs[128 * 32];

    const int tid  = threadIdx.x;
    const int m0   = blockIdx.y * 128;
    const int n0   = blockIdx.x * 128;
    const int wave = tid >> 6, lane = tid & 63;
    const int wm   = (wave >> 1) * 64;
    const int wn   = (wave & 1) * 64;
    const int lm   = lane & 15, quad = lane >> 4;

    f32x4 acc[4][4] = {};

    for (int k0 = 0; k0 < K; k0 += 32) {
        __syncthreads();
        #pragma unroll
        for (int p = 0; p < 2; ++p) {
            int chunk = tid + p * 256;           // 0..511, 16 B each
            int row   = chunk >> 2;
            int off   = (chunk & 3) * 8;
            gl2lds16(&A [(size_t)(m0 + row) * K + k0 + off], &As[chunk * 8]);
            gl2lds16(&Bw[(size_t)(n0 + row) * K + k0 + off], &Bs[chunk * 8]);
        }
        __syncthreads();

        bf16x8 afr[4], bfr[4];
        #pragma unroll
        for (int i = 0; i < 4; ++i)
            afr[i] = *(const bf16x8*)&As[(wm + i * 16 + lm) * 32 + quad * 8];
        #pragma unroll
        for (int j = 0; j < 4; ++j)
            bfr[j] = *(const bf16x8*)&Bs[(wn + j * 16 + lm) * 32 + quad * 8];

        #pragma unroll
        for (int i = 0; i < 4; ++i)
            #pragma unroll
            for (int j = 0; j < 4; ++j)
                acc[i][j] = __builtin_amdgcn_mfma_f32_16x16x32_bf16(afr[i], bfr[j], acc[i][j], 0, 0, 0);
    }

    #pragma unroll
    for (int j = 0; j < 4; ++j) {
        int col = n0 + wn + j * 16 + lm;
        float bv = bias[col];
        #pragma unroll
        for (int i = 0; i < 4; ++i) {
            int rowb = m0 + wm + i * 16 + quad * 4;
            #pragma unroll
            for (int r = 0; r < 4; ++r) {
                float val = acc[i][j][r] + bv;
                if (C_BF16)
                    ((unsigned short*)Cv)[(size_t)(rowb + r) * N + col] = f2bf(val);
                else
                    ((float*)Cv)[(size_t)(rowb + r) * N + col] = val;
            }
        }
    }
}

// ---------------- fallback GEMM (fp32 staging, round-3 proven) ----------------
template<bool A_BF16, bool C_BF16>
__global__ __launch_bounds__(256)
void gemm_bt_bias(const void* __restrict__ Av,
                  const float* __restrict__ Bw,
                  const float* __restrict__ bias,
                  void* __restrict__ Cv,
                  int M, int N, int K)
{
    __shared__ unsigned short As[128 * 40];
    __shared__ unsigned short Bs[128 * 40];

    const int tid  = threadIdx.x;
    const int m0   = blockIdx.y * 128;
    const int n0   = blockIdx.x * 128;
    const int wave = tid >> 6, lane = tid & 63;
    const int wm   = (wave >> 1) * 64;
    const int wn   = (wave & 1) * 64;
    const int lm   = lane & 15, quad = lane >> 4;

    f32x4 acc[4][4] = {};

    for (int k0 = 0; k0 < K; k0 += 32) {
        __syncthreads();
        #pragma unroll
        for (int c = 0; c < 2; ++c) {
            int chunk = tid + c * 256;
            int row   = chunk >> 2;
            int off   = (chunk & 3) * 8;
            if (A_BF16) {
                *(u16x8*)&As[row * 40 + off] =
                    *(const u16x8*)&((const unsigned short*)Av)[(size_t)(m0 + row) * K + k0 + off];
            } else {
                const float* ap = &((const float*)Av)[(size_t)(m0 + row) * K + k0 + off];
                float4 f0 = *(const float4*)ap;
                float4 f1 = *(const float4*)(ap + 4);
                u16x8 h;
                h[0]=f2bf(f0.x); h[1]=f2bf(f0.y); h[2]=f2bf(f0.z); h[3]=f2bf(f0.w);
                h[4]=f2bf(f1.x); h[5]=f2bf(f1.y); h[6]=f2bf(f1.z); h[7]=f2bf(f1.w);
                *(u16x8*)&As[row * 40 + off] = h;
            }
            {
                const float* bp = &Bw[(size_t)(n0 + row) * K + k0 + off];
                float4 f0 = *(const float4*)bp;
                float4 f1 = *(const float4*)(bp + 4);
                u16x8 h;
                h[0]=f2bf(f0.x); h[1]=f2bf(f0.y); h[2]=f2bf(f0.z); h[3]=f2bf(f0.w);
                h[4]=f2bf(f1.x); h[5]=f2bf(f1.y); h[6]=f2bf(f1.z); h[7]=f2bf(f1.w);
                *(u16x8*)&Bs[row * 40 + off] = h;
            }
        }
        __syncthreads();

        bf16x8 afr[4], bfr[4];
        #pragma unroll
        for (int i = 0; i < 4; ++i)
            afr[i] = *(const bf16x8*)&As[(wm + i * 16 + lm) * 40 + quad * 8];
        #pragma unroll
        for (int j = 0; j < 4; ++j)
            bfr[j] = *(const bf16x8*)&Bs[(wn + j * 16 + lm) * 40 + quad * 8];

        #pragma unroll
        for (int i = 0; i < 4; ++i)
            #pragma unroll
            for (int j = 0; j < 4; ++j)
                acc[i][j] = __builtin_amdgcn_mfma_f32_16x16x32_bf16(afr[i], bfr[j], acc[i][j], 0, 0, 0);
    }

    #pragma unroll
    for (int j = 0; j < 4; ++j) {
        int col = n0 + wn + j * 16 + lm;
        float bv = bias[col];
        #pragma unroll
        for (int i = 0; i < 4; ++i) {
            int rowb = m0 + wm + i * 16 + quad * 4;
            #pragma unroll
            for (int r = 0; r < 4; ++r) {
                float val = acc[i][j][r] + bv;
                if (C_BF16)
                    ((unsigned short*)Cv)[(size_t)(rowb + r) * N + col] = f2bf(val);
                else
                    ((float*)Cv)[(size_t)(rowb + r) * N + col] = val;
            }
        }
    }
}

// ---------------- RoPE (in-place on bf16 qkv) ----------------
__global__ __launch_bounds__(256)
void rope_kernel(unsigned short* __restrict__ qkv,
                 const float* __restrict__ cosb,
                 const float* __restrict__ sinb)
{
    int t    = blockIdx.x * 256 + threadIdx.x;
    int d    = t & 63;
    int rest = t >> 6;
    int head = rest % 40;
    int m    = rest / 40;
    int s    = m & (S_ - 1);
    int obase = (head < NH) ? head * D_ : HID + (head - NH) * D_;
    size_t base = (size_t)m * QKV_OUT + obase;

    float x1 = bf2f(qkv[base + d]);
    float x2 = bf2f(qkv[base + d + 64]);
    float c1 = cosb[s * D_ + d];
    float s1 = sinb[s * D_ + d];
    float c2 = cosb[s * D_ + d + 64];
    float s2 = sinb[s * D_ + d + 64];
    qkv[base + d]      = f2bf(x1 * c1 - x2 * s1);
    qkv[base + d + 64] = f2bf(x2 * c2 + x1 * s2);
}

// ---------------- Flash-style MFMA attention (V transposed in LDS) ----------------
__global__ __launch_bounds__(256)
void attn_mfma(const unsigned short* __restrict__ qkv,
               unsigned short* __restrict__ attn)
{
    __shared__ unsigned short Kl[CH * 136];
    __shared__ unsigned short Vt[128 * VSTR];    // [dim][row] transposed
    __shared__ unsigned short Pl[4][16 * 40];

    const int tid  = threadIdx.x;
    const int wave = tid >> 6, lane = tid & 63;
    const int lm   = lane & 15, quad = lane >> 4;
    const int h    = blockIdx.y;
    const int b    = blockIdx.z;
    const int kvh  = h >> 2;
    const int r0b  = blockIdx.x * 64;
    const int rw0  = r0b + wave * 16;

    const size_t qkv_b = (size_t)b * S_ * QKV_OUT;
    const float SCL = 0.12751974f;   // (1/sqrt(128)) * log2(e)

    bf16x8 qf[4];
    {
        const unsigned short* qrow = qkv + qkv_b + (size_t)(rw0 + lm) * QKV_OUT + h * D_ + quad * 8;
        #pragma unroll
        for (int kb = 0; kb < 4; ++kb)
            qf[kb] = *(const bf16x8*)(qrow + kb * 32);
    }

    f32x4 O[8] = {};
    float mrow[4] = {-1e30f, -1e30f, -1e30f, -1e30f};
    float lrow[4] = {0.f, 0.f, 0.f, 0.f};

    const int c0   = max(0, r0b - (WINDOW - 1)) & ~(CH - 1);
    const int cend = r0b + 64 - CH;

    for (int c = c0; c <= cend; c += CH) {
        __syncthreads();
        // K: rows c..c+31, coalesced 16B/lane, padded-136 LDS (conflict-light frag reads)
        #pragma unroll
        for (int p = 0; p < 2; ++p) {
            int idx = tid + p * 256;
            int row = idx >> 4;
            int d0  = (idx & 15) * 8;
            *(u16x8*)&Kl[row * 136 + d0] =
                *(const u16x8*)(qkv + qkv_b + (size_t)(c + row) * QKV_OUT + HID + kvh * D_ + d0);
        }
        // V transposed: thread = 2 rows x 8 dims, packed ds_write_b32 (conflict-free pattern)
        {
            int r2 = (tid & 15) * 2;
            int d0 = (tid >> 4) * 8;
            const unsigned short* vg = qkv + qkv_b + (size_t)(c + r2) * QKV_OUT + HID + NKV * D_ + kvh * D_ + d0;
            u16x8 va = *(const u16x8*)vg;
            u16x8 vb = *(const u16x8*)(vg + QKV_OUT);
            #pragma unroll
            for (int e = 0; e < 8; ++e) {
                unsigned int pack = (unsigned int)va[e] | ((unsigned int)vb[e] << 16);
                *(unsigned int*)&Vt[(d0 + e) * VSTR + r2] = pack;
            }
        }
        __syncthreads();

        if (c + CH - 1 < rw0 - (WINDOW - 1) || c > rw0 + 15) continue;

        // QK^T: two 16-col tiles
        f32x4 s0 = {}, s1 = {};
        #pragma unroll
        for (int kb = 0; kb < 4; ++kb) {
            bf16x8 b0 = *(const bf16x8*)&Kl[lm * 136 + kb * 32 + quad * 8];
            bf16x8 b1 = *(const bf16x8*)&Kl[(16 + lm) * 136 + kb * 32 + quad * 8];
            s0 = __builtin_amdgcn_mfma_f32_16x16x32_bf16(qf[kb], b0, s0, 0, 0, 0);
            s1 = __builtin_amdgcn_mfma_f32_16x16x32_bf16(qf[kb], b1, s1, 0, 0, 0);
        }

        const int j0 = c + lm, j1 = c + 16 + lm;
        float alpha[4];
        #pragma unroll
        for (int r = 0; r < 4; ++r) {
            int row = rw0 + quad * 4 + r;
            float t0 = (j0 <= row && row - j0 < WINDOW) ? s0[r] : -3.0e38f;
            float t1 = (j1 <= row && row - j1 < WINDOW) ? s1[r] : -3.0e38f;
            float cm = fmaxf(t0, t1);
            #pragma unroll
            for (int o = 8; o >= 1; o >>= 1) cm = fmaxf(cm, __shfl_xor(cm, o, 16));
            float mnew = fmaxf(mrow[r], cm);
            float al   = exp2f((mrow[r] - mnew) * SCL);
            float p0   = exp2f((t0 - mnew) * SCL);
            float p1   = exp2f((t1 - mnew) * SCL);
            float rs   = p0 + p1;
            #pragma unroll
            for (int o = 8; o >= 1; o >>= 1) rs += __shfl_xor(rs, o, 16);
            mrow[r] = mnew;
            lrow[r] = lrow[r] * al + rs;
            alpha[r] = al;
            Pl[wave][(quad * 4 + r) * 40 + lm]      = f2bf(p0);
            Pl[wave][(quad * 4 + r) * 40 + 16 + lm] = f2bf(p1);
        }

        #pragma unroll
        for (int nt = 0; nt < 8; ++nt)
            #pragma unroll
            for (int r = 0; r < 4; ++r)
                O[nt][r] *= alpha[r];

        // PV: A = P (wave-private LDS), B = transposed V via ds_read_b128
        bf16x8 pa = *(const bf16x8*)&Pl[wave][lm * 40 + quad * 8];
        #pragma unroll
        for (int nt = 0; nt < 8; ++nt) {
            bf16x8 vbf = *(const bf16x8*)&Vt[(nt * 16 + lm) * VSTR + quad * 8];
            O[nt] = __builtin_amdgcn_mfma_f32_16x16x32_bf16(pa, vbf, O[nt], 0, 0, 0);
        }
    }

    float il[4];
    #pragma unroll
    for (int r = 0; r < 4; ++r) il[r] = 1.0f / lrow[r];
    #pragma unroll
    for (int nt = 0; nt < 8; ++nt)
        #pragma unroll
        for (int r = 0; r < 4; ++r) {
            int row = rw0 + quad * 4 + r;
            attn[(size_t)(b * S_ + row) * (NH * D_) + h * D_ + nt * 16 + lm] = f2bf(O[nt][r] * il[r]);
        }
}

extern "C" void kernel_launch(void* const* d_in, const int* in_sizes, int n_in,
                              void* d_out, int out_size, void* d_ws, size_t ws_size,
                              hipStream_t stream)
{
    const float* hidden = (const float*)d_in[0];
    const float* cosb   = (const float*)d_in[1];
    const float* sinb   = (const float*)d_in[2];
    const float* w_qkv  = (const float*)d_in[3];
    const float* b_qkv  = (const float*)d_in[4];
    const float* w_o    = (const float*)d_in[5];
    const float* b_o    = (const float*)d_in[6];
    float* out = (float*)d_out;

    unsigned char* ws = (unsigned char*)d_ws;
    const size_t QKV_B  = (size_t)M_TOT * QKV_OUT * 2;       // 25.2 MB
    const size_t ATTN_B = (size_t)M_TOT * HID * 2;           // 16.8 MB
    const size_t HB_B   = (size_t)M_TOT * HID * 2;           // 16.8 MB
    const size_t WQ_B   = (size_t)QKV_OUT * HID * 2;         // 50.3 MB
    const size_t WO_B   = (size_t)HID * HID * 2;             // 33.6 MB
    const size_t NEED   = QKV_B + ATTN_B + HB_B + WQ_B;      // wo aliases hb+wq region

    unsigned short* qkv_ws  = (unsigned short*)(ws);
    unsigned short* attn_ws = (unsigned short*)(ws + QKV_B);

    dim3 blk(256);

    if (ws_size >= NEED && WO_B <= HB_B + WQ_B) {
        unsigned short* hb = (unsigned short*)(ws + QKV_B + ATTN_B);
        unsigned short* wq = (unsigned short*)(ws + QKV_B + ATTN_B + HB_B);
        unsigned short* wo = (unsigned short*)(ws + QKV_B + ATTN_B);   // reuse after gemm1

        int n8h = M_TOT * HID / 8;
        int n8q = QKV_OUT * HID / 8;
        int n8o = HID * HID / 8;
        conv_f32_bf16<<<dim3((n8h + 255) / 256), blk, 0, stream>>>(hidden, hb, n8h);
        conv_f32_bf16<<<dim3((n8q + 255) / 256), blk, 0, stream>>>(w_qkv, wq, n8q);
        gemm256_8ph<true><<<dim3(QKV_OUT / 256, M_TOT / 256), dim3(512), 0, stream>>>(
            hb, wq, b_qkv, qkv_ws, M_TOT, QKV_OUT, HID);
        rope_kernel<<<dim3((M_TOT * 40 * 64) / 256), blk, 0, stream>>>(qkv_ws, cosb, sinb);
        conv_f32_bf16<<<dim3((n8o + 255) / 256), blk, 0, stream>>>(w_o, wo, n8o);
        attn_mfma<<<dim3(S_ / 64, NH, B_), blk, 0, stream>>>(qkv_ws, attn_ws);
        gemm_bf16_bt<false><<<dim3(HID / 128, M_TOT / 128), blk, 0, stream>>>(
            attn_ws, wo, b_o, out, M_TOT, HID, NH * D_);
    } else {
        gemm_bt_bias<false, true><<<dim3(QKV_OUT / 128, M_TOT / 128), blk, 0, stream>>>(
            hidden, w_qkv, b_qkv, qkv_ws, M_TOT, QKV_OUT, HID);
        rope_kernel<<<dim3((M_TOT * 40 * 64) / 256), blk, 0, stream>>>(qkv_ws, cosb, sinb);
        attn_mfma<<<dim3(S_ / 64, NH, B_), blk, 0, stream>>>(qkv_ws, attn_ws);
        gemm_bt_bias<true, false><<<dim3(HID / 128, M_TOT / 128), blk, 0, stream>>>(
            attn_ws, w_o, b_o, out, M_TOT, HID, NH * D_);
    }
}

// Round 7
// 517.645 us; speedup vs baseline: 2.0629x; 2.0629x over previous
//
#include <hip/hip_runtime.h>
#include <hip/hip_bf16.h>

#define B_      2
#define S_      1024
#define HID     4096
#define NH      32
#define NKV     8
#define D_      128
#define G_      4
#define WINDOW  512
#define QKV_OUT 6144      // (NH + 2*NKV) * D
#define M_TOT   2048      // B * S
#define CH      32        // kv chunk length in attention
#define VSTR    40        // transposed-V row stride (80 B: 16B-aligned frags, 2-way banks)

typedef __bf16 bf16x8 __attribute__((ext_vector_type(8)));
typedef float  f32x4  __attribute__((ext_vector_type(4)));
typedef unsigned short u16x8 __attribute__((ext_vector_type(8)));

#define AS1 __attribute__((address_space(1)))
#define AS3 __attribute__((address_space(3)))

static __device__ __forceinline__ float bf2f(unsigned short u) {
    union { unsigned int i; float f; } v; v.i = ((unsigned int)u) << 16; return v.f;
}
static __device__ __forceinline__ unsigned short f2bf(float f) {
    union { float f; unsigned int i; } v; v.f = f;
    unsigned int x = v.i;
    return (unsigned short)((x + 0x7fffu + ((x >> 16) & 1u)) >> 16);
}
static __device__ __forceinline__ void gl2lds16(const void* g, void* l) {
    __builtin_amdgcn_global_load_lds((const AS1 void*)g, (AS3 void*)l, 16, 0, 0);
}

// ---------------- fp32 -> bf16 bulk conversion (RTNE) ----------------
__global__ __launch_bounds__(256)
void conv_f32_bf16(const float* __restrict__ src, unsigned short* __restrict__ dst, int n8)
{
    int i = blockIdx.x * 256 + threadIdx.x;
    if (i >= n8) return;
    const float* p = src + (size_t)i * 8;
    float4 f0 = *(const float4*)p;
    float4 f1 = *(const float4*)(p + 4);
    u16x8 h;
    h[0]=f2bf(f0.x); h[1]=f2bf(f0.y); h[2]=f2bf(f0.z); h[3]=f2bf(f0.w);
    h[4]=f2bf(f1.x); h[5]=f2bf(f1.y); h[6]=f2bf(f1.z); h[7]=f2bf(f1.w);
    *(u16x8*)&dst[(size_t)i * 8] = h;
}

// ================= 256x192 4-phase pipelined GEMM =================
// C[M][N] = A[M][K]*Bw[N][K]^T + bias.  BK=64, 512 thr = 8 waves (2M x 4N),
// per-wave C = 128x48 (acc[8][3]).  LDS 112 KiB double-buffered
// (A 2x16384 elem, B 2x12288 elem at +32768).
// Round-6 -> round-7: r6's B-frag double-buffer spilled (acc128+frag96+addr >
// 256 unified VGPR -> WRITE_SIZE 652MB scratch).  Revert to r4 schedule (last
// good, single bC set, boundary reads AFTER P4 barrier) and take the GEOMETRY
// lever instead: BN 256->192 makes grid 32x8 = 256 blocks = exactly 1
// block/CU (was 192 blocks -> 64 CUs idle; LDS-bound 1 block/CU).  Smaller
// acc[8][3]=96 AGPR also ends all spill risk (~185 unified total).
// 3-bit LDS swizzle unchanged (verified 0 conflicts): phys 16B-slot =
// logical slot ^ (row&7); linear gl2lds dest + inverse per-lane global source
// + XOR'd ds_read.  B bases (stage w*1536, read n_*3072, bufoB 12288) keep
// element bits 6-8 clean.
// Ledgers (re-derived for 7 loads/tile/wave = A 2+2, B 2+1):
//   vmcnt: prologue 12 issued, vmcnt(5) drains tile0's 7.  Steady: entry 5 =
//   [B(i+1)x3, A(i+1,rp0)x2]; P1 +2, P2 +2, P3 +1, P4 +2 (stA(i+2,0)) = 12;
//   P4-end vmcnt(5) retires tile i+1's 7 (FIFO).  Tail i=nkt-2: vmcnt(0).
//   lgkm: boundary = 10 reads (B 6 + A01 4), issued at tile end, no wait.
//   P1 wait(4): 10 boundary + 4 aQ -> drains boundary.  P2/P3 wait(4):
//   4 old + 4 new -> drains old.  P4 wait(0): drains aQ67.
// Hazards (r4 proofs, bases re-checked): stB(i+2,*)@P2/P3 vs B(i) boundary
// reads -> drained P1 wait(4) + P1-end bar.  stA(i+2,0)@P4 vs mt0-3 reads ->
// boundary A01 drained P1 wait, aQ23 drained P2 wait; write lands >=HBM-lat
// after P4 issue (r4-validated window).  stA(i+1,1)@P1 vs tile i-1 rows
// 64-127 reads -> P3/P4 waits + P4-end bar.  rdBoundary(i+1) after per-wave
// vmcnt + P4-end bar.  bC WAR: rdBoundary(i+1) is AFTER MFMA(6,7) consumed
// bC (program order) -- the r5 register-WAR bug is structurally absent.
#define MFMA_CL(MT0, MT1, AR)                                                          \
    __builtin_amdgcn_s_setprio(1);                                                     \
    _Pragma("unroll")                                                                  \
    for (int ks = 0; ks < 2; ++ks) {                                                   \
        _Pragma("unroll")                                                              \
        for (int nt = 0; nt < 3; ++nt) {                                               \
            acc[MT0][nt] = __builtin_amdgcn_mfma_f32_16x16x32_bf16(AR[0][ks], bC[nt][ks], acc[MT0][nt], 0, 0, 0); \
            acc[MT1][nt] = __builtin_amdgcn_mfma_f32_16x16x32_bf16(AR[1][ks], bC[nt][ks], acc[MT1][nt], 0, 0, 0); \
        }                                                                              \
    }                                                                                  \
    __builtin_amdgcn_s_setprio(0);

#define SCHED __builtin_amdgcn_sched_barrier(0)
#define WAITLGKM(N) do { asm volatile("s_waitcnt lgkmcnt(" #N ")" ::: "memory"); SCHED; } while (0)
#define BARRIER do { SCHED; __builtin_amdgcn_s_barrier(); SCHED; } while (0)

template<bool C_BF16>
__global__ __launch_bounds__(512, 2)
void gemm256_8ph(const unsigned short* __restrict__ A,
                 const unsigned short* __restrict__ Bw,
                 const float* __restrict__ bias,
                 void* __restrict__ Cv,
                 int M, int N, int K)
{
    __shared__ __attribute__((aligned(1024))) unsigned short lds[57344];  // 112 KiB

    const int tid  = threadIdx.x;
    const int lane = tid & 63;
    const int w    = tid >> 6;        // 0..7
    const int m_   = w >> 2;          // 0..1  (M half, 128 rows)
    const int n_   = w & 3;           // 0..3  (N quarter, 48 cols)
    const int lm   = lane & 15, quad = lane >> 4;
    const int m0   = blockIdx.y * 256, n0 = blockIdx.x * 192;
    const int nkt  = K >> 6;          // BK=64 tiles (requires nkt >= 3)

    // inverse-swizzled global source: lane l fills linear LDS chunk l
    // = phys (row l>>3, slot l&7), holding logical (row l>>3, slot (l&7)^(l>>3))
    const int srow = lane >> 3;                  // 0..7 row within 8-row instr
    const int scol = ((lane & 7) ^ srow) * 8;    // elem col within BK=64

    const int arow0 = m0 + m_ * 128 + n_ * 16;   // staged A rows n_*16..+15
    const int arow1 = arow0 + 64;                // staged A rows 64+n_*16..+15
    const int brow  = n0 + w * 24;               // staged B rows w*24..+23

    const int ldsAr = m_ * 8192;                            // A read base (own half)
    const int ldsA0 = ldsAr + n_ * 1024;                    // A stage rp0
    const int ldsA1 = ldsA0 + 4096;                         // A stage rp1
    const int ldsBs = 32768 + w * 1536;                     // B stage base (24 rows)
    const int ldsBr = 32768 + n_ * 3072;                    // B read base (48 cols)

    f32x4 acc[8][3] = {};
    bf16x8 bC[3][2];           // B frags, whole tile (read at tile boundary)
    bf16x8 aP[2][2], aQ[2][2]; // A frag ping-pong (one phase ahead)

    auto stA = [&](int T, int rp) {
        const int k0   = T << 6;
        const int bufo = (T & 1) << 14;
        const int rb   = (rp ? arow1 : arow0) + srow;
        const int lb   = (rp ? ldsA1 : ldsA0) + bufo + lane * 8;
        gl2lds16(&A[(size_t)rb * K + k0 + scol],       &lds[lb]);
        gl2lds16(&A[(size_t)(rb + 8) * K + k0 + scol], &lds[lb + 512]);
    };
    auto stB = [&](int T, int pr) {        // pr0: rows 0-15 (2 loads), pr1: rows 16-23 (1)
        const int k0   = T << 6;
        const int bufo = (T & 1) * 12288;
        const int rb   = brow + pr * 16 + srow;
        const int lb   = ldsBs + pr * 1024 + bufo + lane * 8;
        gl2lds16(&Bw[(size_t)rb * K + k0 + scol], &lds[lb]);
        if (pr == 0)
            gl2lds16(&Bw[(size_t)(rb + 8) * K + k0 + scol], &lds[lb + 512]);
    };
    auto rdA = [&](int T, int mt, int ks) -> bf16x8 {
        int e = (mt * 16 + lm) * 64 + ks * 32 + quad * 8;
        e ^= ((e >> 6) & 7) << 3;                 // slot ^= row&7 (conflict-free)
        return *(const bf16x8*)&lds[((T & 1) << 14) + ldsAr + e];
    };
    auto rdB = [&](int T, int nt, int ks) -> bf16x8 {
        int e = (nt * 16 + lm) * 64 + ks * 32 + quad * 8;
        e ^= ((e >> 6) & 7) << 3;                 // bases (1536/3072/12288-mult) bits 6-8 clean
        return *(const bf16x8*)&lds[(T & 1) * 12288 + ldsBr + e];
    };
    // boundary reads: B all (6) + A mt0,1 (4) for tile T -- 10 ds_read_b128
    auto rdBoundary = [&](int T) {
        #pragma unroll
        for (int nt = 0; nt < 3; ++nt)
            #pragma unroll
            for (int ks = 0; ks < 2; ++ks) bC[nt][ks] = rdB(T, nt, ks);
        #pragma unroll
        for (int ks = 0; ks < 2; ++ks) { aP[0][ks] = rdA(T, 0, ks); aP[1][ks] = rdA(T, 1, ks); }
    };

    // prologue: tile0 full (7 loads) + tile1 first-5; drain tile0, keep 5 in flight
    stB(0, 0); stB(0, 1); stA(0, 0); stA(0, 1);
    stB(1, 0); stB(1, 1); stA(1, 0);
    asm volatile("s_waitcnt vmcnt(5)" ::: "memory");
    BARRIER;
    rdBoundary(0);
    SCHED;

    #pragma unroll 1
    for (int i = 0; i < nkt; ++i) {
        // ---- P1: MFMA mt0,1 (aP); prefetch mt2,3 -> aQ ----
        if (i + 1 < nkt) stA(i + 1, 1);
        #pragma unroll
        for (int ks = 0; ks < 2; ++ks) { aQ[0][ks] = rdA(i, 2, ks); aQ[1][ks] = rdA(i, 3, ks); }
        SCHED;
        WAITLGKM(4);          // drains boundary 10 (B + A01); leaves aQ's 4
        MFMA_CL(0, 1, aP)
        BARRIER;
        // ---- P2: MFMA mt2,3 (aQ); prefetch mt4,5 -> aP ----  (no end barrier)
        if (i + 2 < nkt) stB(i + 2, 0);
        #pragma unroll
        for (int ks = 0; ks < 2; ++ks) { aP[0][ks] = rdA(i, 4, ks); aP[1][ks] = rdA(i, 5, ks); }
        SCHED;
        WAITLGKM(4);          // drains aQ's 4; leaves aP's 4
        MFMA_CL(2, 3, aQ)
        // ---- P3: MFMA mt4,5 (aP); prefetch mt6,7 -> aQ ----  (no end barrier)
        if (i + 2 < nkt) stB(i + 2, 1);
        #pragma unroll
        for (int ks = 0; ks < 2; ++ks) { aQ[0][ks] = rdA(i, 6, ks); aQ[1][ks] = rdA(i, 7, ks); }
        SCHED;
        WAITLGKM(4);
        MFMA_CL(4, 5, aP)
        // ---- P4: MFMA mt6,7 (aQ); boundary vmcnt; boundary reads for i+1 ----
        if (i + 2 < nkt) stA(i + 2, 0);
        SCHED;
        WAITLGKM(0);          // drains aQ's 4 (only lgkm outstanding)
        MFMA_CL(6, 7, aQ)
        SCHED;
        if (i + 2 < nkt)      { asm volatile("s_waitcnt vmcnt(5)" ::: "memory"); }
        else if (i + 1 < nkt) { asm volatile("s_waitcnt vmcnt(0)" ::: "memory"); }
        BARRIER;
        if (i + 1 < nkt) rdBoundary(i + 1);
        SCHED;
    }

    #pragma unroll
    for (int nt = 0; nt < 3; ++nt) {
        const int col = n0 + n_ * 48 + nt * 16 + lm;
        const float bv = bias[col];
        #pragma unroll
        for (int mt = 0; mt < 8; ++mt) {
            const int rowb = m0 + m_ * 128 + mt * 16 + quad * 4;
            #pragma unroll
            for (int r = 0; r < 4; ++r) {
                const float val = acc[mt][nt][r] + bv;
                if (C_BF16)
                    ((unsigned short*)Cv)[(size_t)(rowb + r) * N + col] = f2bf(val);
                else
                    ((float*)Cv)[(size_t)(rowb + r) * N + col] = val;
            }
        }
    }
}

// ---------------- fast GEMM: bf16 A/B, global_load_lds staging (m97 structure) ----------------
// Kept for the O-projection (M=2048,N=4096): 512-block 128^2 tiling, 2/CU.
template<bool C_BF16>
__global__ __launch_bounds__(256)
void gemm_bf16_bt(const unsigned short* __restrict__ A,
                  const unsigned short* __restrict__ Bw,
                  const float* __restrict__ bias,
                  void* __restrict__ Cv,
                  int M, int N, int K)
{
    __shared__ unsigned short As[128 * 32];   // unpadded: required by global_load_lds lane order
    __shared__ unsigned short Bs[128 * 32];

    const int tid  = threadIdx.x;
    const int m0   = blockIdx.y * 128;
    const int n0   = blockIdx.x * 128;
    const int wave = tid >> 6, lane = tid & 63;
    const int wm   = (wave >> 1) * 64;
    const int wn   = (wave & 1) * 64;
    const int lm   = lane & 15, quad = lane >> 4;

    f32x4 acc[4][4] = {};

    for (int k0 = 0; k0 < K; k0 += 32) {
        __syncthreads();
        #pragma unroll
        for (int p = 0; p < 2; ++p) {
            int chunk = tid + p * 256;           // 0..511, 16 B each
            int row   = chunk >> 2;
            int off   = (chunk & 3) * 8;
            gl2lds16(&A [(size_t)(m0 + row) * K + k0 + off], &As[chunk * 8]);
            gl2lds16(&Bw[(size_t)(n0 + row) * K + k0 + off], &Bs[chunk * 8]);
        }
        __syncthreads();

        bf16x8 afr[4], bfr[4];
        #pragma unroll
        for (int i = 0; i < 4; ++i)
            afr[i] = *(const bf16x8*)&As[(wm + i * 16 + lm) * 32 + quad * 8];
        #pragma unroll
        for (int j = 0; j < 4; ++j)
            bfr[j] = *(const bf16x8*)&Bs[(wn + j * 16 + lm) * 32 + quad * 8];

        #pragma unroll
        for (int i = 0; i < 4; ++i)
            #pragma unroll
            for (int j = 0; j < 4; ++j)
                acc[i][j] = __builtin_amdgcn_mfma_f32_16x16x32_bf16(afr[i], bfr[j], acc[i][j], 0, 0, 0);
    }

    #pragma unroll
    for (int j = 0; j < 4; ++j) {
        int col = n0 + wn + j * 16 + lm;
        float bv = bias[col];
        #pragma unroll
        for (int i = 0; i < 4; ++i) {
            int rowb = m0 + wm + i * 16 + quad * 4;
            #pragma unroll
            for (int r = 0; r < 4; ++r) {
                float val = acc[i][j][r] + bv;
                if (C_BF16)
                    ((unsigned short*)Cv)[(size_t)(rowb + r) * N + col] = f2bf(val);
                else
                    ((float*)Cv)[(size_t)(rowb + r) * N + col] = val;
            }
        }
    }
}

// ---------------- fallback GEMM (fp32 staging, round-3 proven) ----------------
template<bool A_BF16, bool C_BF16>
__global__ __launch_bounds__(256)
void gemm_bt_bias(const void* __restrict__ Av,
                  const float* __restrict__ Bw,
                  const float* __restrict__ bias,
                  void* __restrict__ Cv,
                  int M, int N, int K)
{
    __shared__ unsigned short As[128 * 40];
    __shared__ unsigned short Bs[128 * 40];

    const int tid  = threadIdx.x;
    const int m0   = blockIdx.y * 128;
    const int n0   = blockIdx.x * 128;
    const int wave = tid >> 6, lane = tid & 63;
    const int wm   = (wave >> 1) * 64;
    const int wn   = (wave & 1) * 64;
    const int lm   = lane & 15, quad = lane >> 4;

    f32x4 acc[4][4] = {};

    for (int k0 = 0; k0 < K; k0 += 32) {
        __syncthreads();
        #pragma unroll
        for (int c = 0; c < 2; ++c) {
            int chunk = tid + c * 256;
            int row   = chunk >> 2;
            int off   = (chunk & 3) * 8;
            if (A_BF16) {
                *(u16x8*)&As[row * 40 + off] =
                    *(const u16x8*)&((const unsigned short*)Av)[(size_t)(m0 + row) * K + k0 + off];
            } else {
                const float* ap = &((const float*)Av)[(size_t)(m0 + row) * K + k0 + off];
                float4 f0 = *(const float4*)ap;
                float4 f1 = *(const float4*)(ap + 4);
                u16x8 h;
                h[0]=f2bf(f0.x); h[1]=f2bf(f0.y); h[2]=f2bf(f0.z); h[3]=f2bf(f0.w);
                h[4]=f2bf(f1.x); h[5]=f2bf(f1.y); h[6]=f2bf(f1.z); h[7]=f2bf(f1.w);
                *(u16x8*)&As[row * 40 + off] = h;
            }
            {
                const float* bp = &Bw[(size_t)(n0 + row) * K + k0 + off];
                float4 f0 = *(const float4*)bp;
                float4 f1 = *(const float4*)(bp + 4);
                u16x8 h;
                h[0]=f2bf(f0.x); h[1]=f2bf(f0.y); h[2]=f2bf(f0.z); h[3]=f2bf(f0.w);
                h[4]=f2bf(f1.x); h[5]=f2bf(f1.y); h[6]=f2bf(f1.z); h[7]=f2bf(f1.w);
                *(u16x8*)&Bs[row * 40 + off] = h;
            }
        }
        __syncthreads();

        bf16x8 afr[4], bfr[4];
        #pragma unroll
        for (int i = 0; i < 4; ++i)
            afr[i] = *(const bf16x8*)&As[(wm + i * 16 + lm) * 40 + quad * 8];
        #pragma unroll
        for (int j = 0; j < 4; ++j)
            bfr[j] = *(const bf16x8*)&Bs[(wn + j * 16 + lm) * 40 + quad * 8];

        #pragma unroll
        for (int i = 0; i < 4; ++i)
            #pragma unroll
            for (int j = 0; j < 4; ++j)
                acc[i][j] = __builtin_amdgcn_mfma_f32_16x16x32_bf16(afr[i], bfr[j], acc[i][j], 0, 0, 0);
    }

    #pragma unroll
    for (int j = 0; j < 4; ++j) {
        int col = n0 + wn + j * 16 + lm;
        float bv = bias[col];
        #pragma unroll
        for (int i = 0; i < 4; ++i) {
            int rowb = m0 + wm + i * 16 + quad * 4;
            #pragma unroll
            for (int r = 0; r < 4; ++r) {
                float val = acc[i][j][r] + bv;
                if (C_BF16)
                    ((unsigned short*)Cv)[(size_t)(rowb + r) * N + col] = f2bf(val);
                else
                    ((float*)Cv)[(size_t)(rowb + r) * N + col] = val;
            }
        }
    }
}

// ---------------- RoPE (in-place on bf16 qkv) ----------------
__global__ __launch_bounds__(256)
void rope_kernel(unsigned short* __restrict__ qkv,
                 const float* __restrict__ cosb,
                 const float* __restrict__ sinb)
{
    int t    = blockIdx.x * 256 + threadIdx.x;
    int d    = t & 63;
    int rest = t >> 6;
    int head = rest % 40;
    int m    = rest / 40;
    int s    = m & (S_ - 1);
    int obase = (head < NH) ? head * D_ : HID + (head - NH) * D_;
    size_t base = (size_t)m * QKV_OUT + obase;

    float x1 = bf2f(qkv[base + d]);
    float x2 = bf2f(qkv[base + d + 64]);
    float c1 = cosb[s * D_ + d];
    float s1 = sinb[s * D_ + d];
    float c2 = cosb[s * D_ + d + 64];
    float s2 = sinb[s * D_ + d + 64];
    qkv[base + d]      = f2bf(x1 * c1 - x2 * s1);
    qkv[base + d + 64] = f2bf(x2 * c2 + x1 * s2);
}

// ---------------- Flash-style MFMA attention (V transposed in LDS) ----------------
__global__ __launch_bounds__(256)
void attn_mfma(const unsigned short* __restrict__ qkv,
               unsigned short* __restrict__ attn)
{
    __shared__ unsigned short Kl[CH * 136];
    __shared__ unsigned short Vt[128 * VSTR];    // [dim][row] transposed
    __shared__ unsigned short Pl[4][16 * 40];

    const int tid  = threadIdx.x;
    const int wave = tid >> 6, lane = tid & 63;
    const int lm   = lane & 15, quad = lane >> 4;
    const int h    = blockIdx.y;
    const int b    = blockIdx.z;
    const int kvh  = h >> 2;
    const int r0b  = blockIdx.x * 64;
    const int rw0  = r0b + wave * 16;

    const size_t qkv_b = (size_t)b * S_ * QKV_OUT;
    const float SCL = 0.12751974f;   // (1/sqrt(128)) * log2(e)

    bf16x8 qf[4];
    {
        const unsigned short* qrow = qkv + qkv_b + (size_t)(rw0 + lm) * QKV_OUT + h * D_ + quad * 8;
        #pragma unroll
        for (int kb = 0; kb < 4; ++kb)
            qf[kb] = *(const bf16x8*)(qrow + kb * 32);
    }

    f32x4 O[8] = {};
    float mrow[4] = {-1e30f, -1e30f, -1e30f, -1e30f};
    float lrow[4] = {0.f, 0.f, 0.f, 0.f};

    const int c0   = max(0, r0b - (WINDOW - 1)) & ~(CH - 1);
    const int cend = r0b + 64 - CH;

    for (int c = c0; c <= cend; c += CH) {
        __syncthreads();
        // K: rows c..c+31, coalesced 16B/lane, padded-136 LDS (conflict-light frag reads)
        #pragma unroll
        for (int p = 0; p < 2; ++p) {
            int idx = tid + p * 256;
            int row = idx >> 4;
            int d0  = (idx & 15) * 8;
            *(u16x8*)&Kl[row * 136 + d0] =
                *(const u16x8*)(qkv + qkv_b + (size_t)(c + row) * QKV_OUT + HID + kvh * D_ + d0);
        }
        // V transposed: thread = 2 rows x 8 dims, packed ds_write_b32 (conflict-free pattern)
        {
            int r2 = (tid & 15) * 2;
            int d0 = (tid >> 4) * 8;
            const unsigned short* vg = qkv + qkv_b + (size_t)(c + r2) * QKV_OUT + HID + NKV * D_ + kvh * D_ + d0;
            u16x8 va = *(const u16x8*)vg;
            u16x8 vb = *(const u16x8*)(vg + QKV_OUT);
            #pragma unroll
            for (int e = 0; e < 8; ++e) {
                unsigned int pack = (unsigned int)va[e] | ((unsigned int)vb[e] << 16);
                *(unsigned int*)&Vt[(d0 + e) * VSTR + r2] = pack;
            }
        }
        __syncthreads();

        if (c + CH - 1 < rw0 - (WINDOW - 1) || c > rw0 + 15) continue;

        // QK^T: two 16-col tiles
        f32x4 s0 = {}, s1 = {};
        #pragma unroll
        for (int kb = 0; kb < 4; ++kb) {
            bf16x8 b0 = *(const bf16x8*)&Kl[lm * 136 + kb * 32 + quad * 8];
            bf16x8 b1 = *(const bf16x8*)&Kl[(16 + lm) * 136 + kb * 32 + quad * 8];
            s0 = __builtin_amdgcn_mfma_f32_16x16x32_bf16(qf[kb], b0, s0, 0, 0, 0);
            s1 = __builtin_amdgcn_mfma_f32_16x16x32_bf16(qf[kb], b1, s1, 0, 0, 0);
        }

        const int j0 = c + lm, j1 = c + 16 + lm;
        float alpha[4];
        #pragma unroll
        for (int r = 0; r < 4; ++r) {
            int row = rw0 + quad * 4 + r;
            float t0 = (j0 <= row && row - j0 < WINDOW) ? s0[r] : -3.0e38f;
            float t1 = (j1 <= row && row - j1 < WINDOW) ? s1[r] : -3.0e38f;
            float cm = fmaxf(t0, t1);
            #pragma unroll
            for (int o = 8; o >= 1; o >>= 1) cm = fmaxf(cm, __shfl_xor(cm, o, 16));
            float mnew = fmaxf(mrow[r], cm);
            float al   = exp2f((mrow[r] - mnew) * SCL);
            float p0   = exp2f((t0 - mnew) * SCL);
            float p1   = exp2f((t1 - mnew) * SCL);
            float rs   = p0 + p1;
            #pragma unroll
            for (int o = 8; o >= 1; o >>= 1) rs += __shfl_xor(rs, o, 16);
            mrow[r] = mnew;
            lrow[r] = lrow[r] * al + rs;
            alpha[r] = al;
            Pl[wave][(quad * 4 + r) * 40 + lm]      = f2bf(p0);
            Pl[wave][(quad * 4 + r) * 40 + 16 + lm] = f2bf(p1);
        }

        #pragma unroll
        for (int nt = 0; nt < 8; ++nt)
            #pragma unroll
            for (int r = 0; r < 4; ++r)
                O[nt][r] *= alpha[r];

        // PV: A = P (wave-private LDS), B = transposed V via ds_read_b128
        bf16x8 pa = *(const bf16x8*)&Pl[wave][lm * 40 + quad * 8];
        #pragma unroll
        for (int nt = 0; nt < 8; ++nt) {
            bf16x8 vbf = *(const bf16x8*)&Vt[(nt * 16 + lm) * VSTR + quad * 8];
            O[nt] = __builtin_amdgcn_mfma_f32_16x16x32_bf16(pa, vbf, O[nt], 0, 0, 0);
        }
    }

    float il[4];
    #pragma unroll
    for (int r = 0; r < 4; ++r) il[r] = 1.0f / lrow[r];
    #pragma unroll
    for (int nt = 0; nt < 8; ++nt)
        #pragma unroll
        for (int r = 0; r < 4; ++r) {
            int row = rw0 + quad * 4 + r;
            attn[(size_t)(b * S_ + row) * (NH * D_) + h * D_ + nt * 16 + lm] = f2bf(O[nt][r] * il[r]);
        }
}

extern "C" void kernel_launch(void* const* d_in, const int* in_sizes, int n_in,
                              void* d_out, int out_size, void* d_ws, size_t ws_size,
                              hipStream_t stream)
{
    const float* hidden = (const float*)d_in[0];
    const float* cosb   = (const float*)d_in[1];
    const float* sinb   = (const float*)d_in[2];
    const float* w_qkv  = (const float*)d_in[3];
    const float* b_qkv  = (const float*)d_in[4];
    const float* w_o    = (const float*)d_in[5];
    const float* b_o    = (const float*)d_in[6];
    float* out = (float*)d_out;

    unsigned char* ws = (unsigned char*)d_ws;
    const size_t QKV_B  = (size_t)M_TOT * QKV_OUT * 2;       // 25.2 MB
    const size_t ATTN_B = (size_t)M_TOT * HID * 2;           // 16.8 MB
    const size_t HB_B   = (size_t)M_TOT * HID * 2;           // 16.8 MB
    const size_t WQ_B   = (size_t)QKV_OUT * HID * 2;         // 50.3 MB
    const size_t WO_B   = (size_t)HID * HID * 2;             // 33.6 MB
    const size_t NEED   = QKV_B + ATTN_B + HB_B + WQ_B;      // wo aliases hb+wq region

    unsigned short* qkv_ws  = (unsigned short*)(ws);
    unsigned short* attn_ws = (unsigned short*)(ws + QKV_B);

    dim3 blk(256);

    if (ws_size >= NEED && WO_B <= HB_B + WQ_B) {
        unsigned short* hb = (unsigned short*)(ws + QKV_B + ATTN_B);
        unsigned short* wq = (unsigned short*)(ws + QKV_B + ATTN_B + HB_B);
        unsigned short* wo = (unsigned short*)(ws + QKV_B + ATTN_B);   // reuse after gemm1

        int n8h = M_TOT * HID / 8;
        int n8q = QKV_OUT * HID / 8;
        int n8o = HID * HID / 8;
        conv_f32_bf16<<<dim3((n8h + 255) / 256), blk, 0, stream>>>(hidden, hb, n8h);
        conv_f32_bf16<<<dim3((n8q + 255) / 256), blk, 0, stream>>>(w_qkv, wq, n8q);
        gemm256_8ph<true><<<dim3(QKV_OUT / 192, M_TOT / 256), dim3(512), 0, stream>>>(
            hb, wq, b_qkv, qkv_ws, M_TOT, QKV_OUT, HID);
        rope_kernel<<<dim3((M_TOT * 40 * 64) / 256), blk, 0, stream>>>(qkv_ws, cosb, sinb);
        conv_f32_bf16<<<dim3((n8o + 255) / 256), blk, 0, stream>>>(w_o, wo, n8o);
        attn_mfma<<<dim3(S_ / 64, NH, B_), blk, 0, stream>>>(qkv_ws, attn_ws);
        gemm_bf16_bt<false><<<dim3(HID / 128, M_TOT / 128), blk, 0, stream>>>(
            attn_ws, wo, b_o, out, M_TOT, HID, NH * D_);
    } else {
        gemm_bt_bias<false, true><<<dim3(QKV_OUT / 128, M_TOT / 128), blk, 0, stream>>>(
            hidden, w_qkv, b_qkv, qkv_ws, M_TOT, QKV_OUT, HID);
        rope_kernel<<<dim3((M_TOT * 40 * 64) / 256), blk, 0, stream>>>(qkv_ws, cosb, sinb);
        attn_mfma<<<dim3(S_ / 64, NH, B_), blk, 0, stream>>>(qkv_ws, attn_ws);
        gemm_bt_bias<true, false><<<dim3(HID / 128, M_TOT / 128), blk, 0, stream>>>(
            attn_ws, w_o, b_o, out, M_TOT, HID, NH * D_);
    }
}

// Round 8
// 490.083 us; speedup vs baseline: 2.1789x; 1.0562x over previous
//
#include <hip/hip_runtime.h>
#include <hip/hip_bf16.h>

#define B_      2
#define S_      1024
#define HID     4096
#define NH      32
#define NKV     8
#define D_      128
#define G_      4
#define WINDOW  512
#define QKV_OUT 6144      // (NH + 2*NKV) * D
#define M_TOT   2048      // B * S
#define CH      32        // kv chunk length in attention
#define VSTR    40        // transposed-V row stride (80 B: 16B-aligned frags, 2-way banks)

typedef __bf16 bf16x8 __attribute__((ext_vector_type(8)));
typedef float  f32x4  __attribute__((ext_vector_type(4)));
typedef unsigned short u16x8 __attribute__((ext_vector_type(8)));

#define AS1 __attribute__((address_space(1)))
#define AS3 __attribute__((address_space(3)))

static __device__ __forceinline__ float bf2f(unsigned short u) {
    union { unsigned int i; float f; } v; v.i = ((unsigned int)u) << 16; return v.f;
}
static __device__ __forceinline__ unsigned short f2bf(float f) {
    union { float f; unsigned int i; } v; v.f = f;
    unsigned int x = v.i;
    return (unsigned short)((x + 0x7fffu + ((x >> 16) & 1u)) >> 16);
}
static __device__ __forceinline__ void gl2lds16(const void* g, void* l) {
    __builtin_amdgcn_global_load_lds((const AS1 void*)g, (AS3 void*)l, 16, 0, 0);
}

// ---------------- fp32 -> bf16 bulk conversion (RTNE) ----------------
__global__ __launch_bounds__(256)
void conv_f32_bf16(const float* __restrict__ src, unsigned short* __restrict__ dst, int n8)
{
    int i = blockIdx.x * 256 + threadIdx.x;
    if (i >= n8) return;
    const float* p = src + (size_t)i * 8;
    float4 f0 = *(const float4*)p;
    float4 f1 = *(const float4*)(p + 4);
    u16x8 h;
    h[0]=f2bf(f0.x); h[1]=f2bf(f0.y); h[2]=f2bf(f0.z); h[3]=f2bf(f0.w);
    h[4]=f2bf(f1.x); h[5]=f2bf(f1.y); h[6]=f2bf(f1.z); h[7]=f2bf(f1.w);
    *(u16x8*)&dst[(size_t)i * 8] = h;
}

// ================= 256 x (NT*64) 4-phase pipelined GEMM =================
// C[M][N] = A[M][K]*Bw[N][K]^T + bias.  BK=64, 512 thr = 8 waves (2M x 4N),
// per-wave C = 128 x NT*16 (acc[8][NT]).  Template NT: 3 -> BN=192 (QKV,
// r7-proven at grid 32x8=256=1/CU), 2 -> BN=128 (O-projection, grid
// 4096/128 x 2048/256 = 32x8 = 256 = 1/CU, replacing the m97-structure
// 128^2 kernel: 115us, MfmaUtil 25%, 8.4e6 bank conflicts).
// Structure is LDS-issue-bound (~12 cyc/ds_read_b128); NT=2 issues 160
// reads/tile/CU vs NT=3's 208 -> predicted ~78-88us for the O shape.
// LDS: A 2buf x 16384 elem at 0; B 2buf x NT*4096 at +32768.  Total
// 64 + NT*16 KiB (NT=3: 112 KiB, NT=2: 96 KiB) -> 1 block/CU either way.
// 3-bit LDS swizzle (r2-verified 0 conflicts): phys 16B-slot = logical
// slot ^ (row&7); linear gl2lds dest + inverse per-lane global source +
// XOR'd ds_read.  All B bases (w*NT*512 stage, n_*NT*1024 read, NT*4096
// buf) are 512-elem multiples -> element bits 6-8 clean, swizzle intact.
// Ledgers (generic, loads/tile/wave = NT+4: A 2+2, B (NT-1)+1):
//   vmcnt: prologue issues (NT+4)+(NT+2); vmcnt(NT+2) drains tile0's NT+4.
//   Steady entry NT+2 = [B(i+1) x NT, A(i+1,rp0) x2]; P1 +2, P2 +(NT-1),
//   P3 +1, P4 +2; P4-end vmcnt(NT+2) retires tile i+1's NT+4 (FIFO).
//   Tail i=nkt-2: vmcnt(0).  Never 0 mid-loop.
//   lgkm: boundary = 2NT+4 reads, issued at tile end, no wait.  P1 wait(4):
//   boundary + 4 aQ -> drains boundary.  P2/P3 wait(4): 4 old + 4 new ->
//   drains old.  P4 wait(0): drains aQ67.
// Hazards (r4/r7 proofs, structure unchanged): stB(i+2,*)@P2/P3 vs B(i)
// boundary reads -> drained P1 wait(4) + P1-end bar.  stA(i+2,0)@P4 vs
// mt0-3 reads -> drained <= P2 wait.  stA(i+1,1)@P1 vs tile i-1 rows 64-127
// -> P3/P4 waits + P4-end bar.  rdBoundary(i+1) after per-wave vmcnt +
// P4-end bar.  bC WAR structurally absent (boundary reads AFTER MFMA(6,7)).
#define MFMA_CL(MT0, MT1, AR)                                                          \
    __builtin_amdgcn_s_setprio(1);                                                     \
    _Pragma("unroll")                                                                  \
    for (int ks = 0; ks < 2; ++ks) {                                                   \
        _Pragma("unroll")                                                              \
        for (int nt = 0; nt < NT; ++nt) {                                              \
            acc[MT0][nt] = __builtin_amdgcn_mfma_f32_16x16x32_bf16(AR[0][ks], bC[nt][ks], acc[MT0][nt], 0, 0, 0); \
            acc[MT1][nt] = __builtin_amdgcn_mfma_f32_16x16x32_bf16(AR[1][ks], bC[nt][ks], acc[MT1][nt], 0, 0, 0); \
        }                                                                              \
    }                                                                                  \
    __builtin_amdgcn_s_setprio(0);

#define SCHED __builtin_amdgcn_sched_barrier(0)
#define WAITLGKM(N) do { asm volatile("s_waitcnt lgkmcnt(" #N ")" ::: "memory"); SCHED; } while (0)
#define WAITVM_STEADY do {                                                             \
    if constexpr (NT == 3) { asm volatile("s_waitcnt vmcnt(5)" ::: "memory"); }        \
    else                   { asm volatile("s_waitcnt vmcnt(4)" ::: "memory"); }        \
} while (0)
#define BARRIER do { SCHED; __builtin_amdgcn_s_barrier(); SCHED; } while (0)

template<int NT, bool C_BF16>
__global__ __launch_bounds__(512, 2)
void gemm256_8ph(const unsigned short* __restrict__ A,
                 const unsigned short* __restrict__ Bw,
                 const float* __restrict__ bias,
                 void* __restrict__ Cv,
                 int M, int N, int K)
{
    __shared__ __attribute__((aligned(1024))) unsigned short lds[32768 + NT * 8192];

    const int tid  = threadIdx.x;
    const int lane = tid & 63;
    const int w    = tid >> 6;        // 0..7
    const int m_   = w >> 2;          // 0..1  (M half, 128 rows)
    const int n_   = w & 3;           // 0..3  (N quarter, NT*16 cols)
    const int lm   = lane & 15, quad = lane >> 4;
    const int m0   = blockIdx.y * 256, n0 = blockIdx.x * (NT * 64);
    const int nkt  = K >> 6;          // BK=64 tiles (requires nkt >= 3)

    // inverse-swizzled global source: lane l fills linear LDS chunk l
    // = phys (row l>>3, slot l&7), holding logical (row l>>3, slot (l&7)^(l>>3))
    const int srow = lane >> 3;                  // 0..7 row within 8-row instr
    const int scol = ((lane & 7) ^ srow) * 8;    // elem col within BK=64

    const int arow0 = m0 + m_ * 128 + n_ * 16;   // staged A rows n_*16..+15
    const int arow1 = arow0 + 64;                // staged A rows 64+n_*16..+15
    const int brow  = n0 + w * (NT * 8);         // staged B rows, NT*8 per wave

    const int ldsAr = m_ * 8192;                            // A read base (own half)
    const int ldsA0 = ldsAr + n_ * 1024;                    // A stage rp0
    const int ldsA1 = ldsA0 + 4096;                         // A stage rp1
    const int ldsBs = 32768 + w * (NT * 512);               // B stage base
    const int ldsBr = 32768 + n_ * (NT * 1024);             // B read base

    f32x4 acc[8][NT] = {};
    bf16x8 bC[NT][2];          // B frags, whole tile (read at tile boundary)
    bf16x8 aP[2][2], aQ[2][2]; // A frag ping-pong (one phase ahead)

    auto stA = [&](int T, int rp) {
        const int k0   = T << 6;
        const int bufo = (T & 1) << 14;
        const int rb   = (rp ? arow1 : arow0) + srow;
        const int lb   = (rp ? ldsA1 : ldsA0) + bufo + lane * 8;
        gl2lds16(&A[(size_t)rb * K + k0 + scol],       &lds[lb]);
        gl2lds16(&A[(size_t)(rb + 8) * K + k0 + scol], &lds[lb + 512]);
    };
    auto stB = [&](int T, int pr) {   // pr0: first NT-1 loads, pr1: last 8 rows (1 load)
        const int k0   = T << 6;
        const int bufo = (T & 1) * (NT * 4096);
        if (pr == 0) {
            #pragma unroll
            for (int j = 0; j < NT - 1; ++j) {
                const int rb = brow + j * 8 + srow;
                gl2lds16(&Bw[(size_t)rb * K + k0 + scol],
                         &lds[ldsBs + j * 512 + bufo + lane * 8]);
            }
        } else {
            const int rb = brow + (NT - 1) * 8 + srow;
            gl2lds16(&Bw[(size_t)rb * K + k0 + scol],
                     &lds[ldsBs + (NT - 1) * 512 + bufo + lane * 8]);
        }
    };
    auto rdA = [&](int T, int mt, int ks) -> bf16x8 {
        int e = (mt * 16 + lm) * 64 + ks * 32 + quad * 8;
        e ^= ((e >> 6) & 7) << 3;                 // slot ^= row&7 (conflict-free)
        return *(const bf16x8*)&lds[((T & 1) << 14) + ldsAr + e];
    };
    auto rdB = [&](int T, int nt, int ks) -> bf16x8 {
        int e = (nt * 16 + lm) * 64 + ks * 32 + quad * 8;
        e ^= ((e >> 6) & 7) << 3;                 // all bases 512-elem mult: bits 6-8 clean
        return *(const bf16x8*)&lds[(T & 1) * (NT * 4096) + ldsBr + e];
    };
    // boundary reads: B all (2*NT) + A mt0,1 (4) for tile T
    auto rdBoundary = [&](int T) {
        #pragma unroll
        for (int nt = 0; nt < NT; ++nt)
            #pragma unroll
            for (int ks = 0; ks < 2; ++ks) bC[nt][ks] = rdB(T, nt, ks);
        #pragma unroll
        for (int ks = 0; ks < 2; ++ks) { aP[0][ks] = rdA(T, 0, ks); aP[1][ks] = rdA(T, 1, ks); }
    };

    // prologue: tile0 full (NT+4 loads) + tile1 first NT+2; drain tile0
    stB(0, 0); stB(0, 1); stA(0, 0); stA(0, 1);
    stB(1, 0); stB(1, 1); stA(1, 0);
    WAITVM_STEADY;
    BARRIER;
    rdBoundary(0);
    SCHED;

    #pragma unroll 1
    for (int i = 0; i < nkt; ++i) {
        // ---- P1: MFMA mt0,1 (aP); prefetch mt2,3 -> aQ ----
        if (i + 1 < nkt) stA(i + 1, 1);
        #pragma unroll
        for (int ks = 0; ks < 2; ++ks) { aQ[0][ks] = rdA(i, 2, ks); aQ[1][ks] = rdA(i, 3, ks); }
        SCHED;
        WAITLGKM(4);          // drains boundary (2NT+4); leaves aQ's 4
        MFMA_CL(0, 1, aP)
        BARRIER;
        // ---- P2: MFMA mt2,3 (aQ); prefetch mt4,5 -> aP ----  (no end barrier)
        if (i + 2 < nkt) stB(i + 2, 0);
        #pragma unroll
        for (int ks = 0; ks < 2; ++ks) { aP[0][ks] = rdA(i, 4, ks); aP[1][ks] = rdA(i, 5, ks); }
        SCHED;
        WAITLGKM(4);          // drains aQ's 4; leaves aP's 4
        MFMA_CL(2, 3, aQ)
        // ---- P3: MFMA mt4,5 (aP); prefetch mt6,7 -> aQ ----  (no end barrier)
        if (i + 2 < nkt) stB(i + 2, 1);
        #pragma unroll
        for (int ks = 0; ks < 2; ++ks) { aQ[0][ks] = rdA(i, 6, ks); aQ[1][ks] = rdA(i, 7, ks); }
        SCHED;
        WAITLGKM(4);
        MFMA_CL(4, 5, aP)
        // ---- P4: MFMA mt6,7 (aQ); boundary vmcnt; boundary reads for i+1 ----
        if (i + 2 < nkt) stA(i + 2, 0);
        SCHED;
        WAITLGKM(0);          // drains aQ's 4 (only lgkm outstanding)
        MFMA_CL(6, 7, aQ)
        SCHED;
        if (i + 2 < nkt)      { WAITVM_STEADY; }
        else if (i + 1 < nkt) { asm volatile("s_waitcnt vmcnt(0)" ::: "memory"); }
        BARRIER;
        if (i + 1 < nkt) rdBoundary(i + 1);
        SCHED;
    }

    #pragma unroll
    for (int nt = 0; nt < NT; ++nt) {
        const int col = n0 + n_ * (NT * 16) + nt * 16 + lm;
        const float bv = bias[col];
        #pragma unroll
        for (int mt = 0; mt < 8; ++mt) {
            const int rowb = m0 + m_ * 128 + mt * 16 + quad * 4;
            #pragma unroll
            for (int r = 0; r < 4; ++r) {
                const float val = acc[mt][nt][r] + bv;
                if (C_BF16)
                    ((unsigned short*)Cv)[(size_t)(rowb + r) * N + col] = f2bf(val);
                else
                    ((float*)Cv)[(size_t)(rowb + r) * N + col] = val;
            }
        }
    }
}

// ---------------- fallback GEMM (fp32 staging, round-3 proven) ----------------
template<bool A_BF16, bool C_BF16>
__global__ __launch_bounds__(256)
void gemm_bt_bias(const void* __restrict__ Av,
                  const float* __restrict__ Bw,
                  const float* __restrict__ bias,
                  void* __restrict__ Cv,
                  int M, int N, int K)
{
    __shared__ unsigned short As[128 * 40];
    __shared__ unsigned short Bs[128 * 40];

    const int tid  = threadIdx.x;
    const int m0   = blockIdx.y * 128;
    const int n0   = blockIdx.x * 128;
    const int wave = tid >> 6, lane = tid & 63;
    const int wm   = (wave >> 1) * 64;
    const int wn   = (wave & 1) * 64;
    const int lm   = lane & 15, quad = lane >> 4;

    f32x4 acc[4][4] = {};

    for (int k0 = 0; k0 < K; k0 += 32) {
        __syncthreads();
        #pragma unroll
        for (int c = 0; c < 2; ++c) {
            int chunk = tid + c * 256;
            int row   = chunk >> 2;
            int off   = (chunk & 3) * 8;
            if (A_BF16) {
                *(u16x8*)&As[row * 40 + off] =
                    *(const u16x8*)&((const unsigned short*)Av)[(size_t)(m0 + row) * K + k0 + off];
            } else {
                const float* ap = &((const float*)Av)[(size_t)(m0 + row) * K + k0 + off];
                float4 f0 = *(const float4*)ap;
                float4 f1 = *(const float4*)(ap + 4);
                u16x8 h;
                h[0]=f2bf(f0.x); h[1]=f2bf(f0.y); h[2]=f2bf(f0.z); h[3]=f2bf(f0.w);
                h[4]=f2bf(f1.x); h[5]=f2bf(f1.y); h[6]=f2bf(f1.z); h[7]=f2bf(f1.w);
                *(u16x8*)&As[row * 40 + off] = h;
            }
            {
                const float* bp = &Bw[(size_t)(n0 + row) * K + k0 + off];
                float4 f0 = *(const float4*)bp;
                float4 f1 = *(const float4*)(bp + 4);
                u16x8 h;
                h[0]=f2bf(f0.x); h[1]=f2bf(f0.y); h[2]=f2bf(f0.z); h[3]=f2bf(f0.w);
                h[4]=f2bf(f1.x); h[5]=f2bf(f1.y); h[6]=f2bf(f1.z); h[7]=f2bf(f1.w);
                *(u16x8*)&Bs[row * 40 + off] = h;
            }
        }
        __syncthreads();

        bf16x8 afr[4], bfr[4];
        #pragma unroll
        for (int i = 0; i < 4; ++i)
            afr[i] = *(const bf16x8*)&As[(wm + i * 16 + lm) * 40 + quad * 8];
        #pragma unroll
        for (int j = 0; j < 4; ++j)
            bfr[j] = *(const bf16x8*)&Bs[(wn + j * 16 + lm) * 40 + quad * 8];

        #pragma unroll
        for (int i = 0; i < 4; ++i)
            #pragma unroll
            for (int j = 0; j < 4; ++j)
                acc[i][j] = __builtin_amdgcn_mfma_f32_16x16x32_bf16(afr[i], bfr[j], acc[i][j], 0, 0, 0);
    }

    #pragma unroll
    for (int j = 0; j < 4; ++j) {
        int col = n0 + wn + j * 16 + lm;
        float bv = bias[col];
        #pragma unroll
        for (int i = 0; i < 4; ++i) {
            int rowb = m0 + wm + i * 16 + quad * 4;
            #pragma unroll
            for (int r = 0; r < 4; ++r) {
                float val = acc[i][j][r] + bv;
                if (C_BF16)
                    ((unsigned short*)Cv)[(size_t)(rowb + r) * N + col] = f2bf(val);
                else
                    ((float*)Cv)[(size_t)(rowb + r) * N + col] = val;
            }
        }
    }
}

// ---------------- RoPE (in-place on bf16 qkv) ----------------
__global__ __launch_bounds__(256)
void rope_kernel(unsigned short* __restrict__ qkv,
                 const float* __restrict__ cosb,
                 const float* __restrict__ sinb)
{
    int t    = blockIdx.x * 256 + threadIdx.x;
    int d    = t & 63;
    int rest = t >> 6;
    int head = rest % 40;
    int m    = rest / 40;
    int s    = m & (S_ - 1);
    int obase = (head < NH) ? head * D_ : HID + (head - NH) * D_;
    size_t base = (size_t)m * QKV_OUT + obase;

    float x1 = bf2f(qkv[base + d]);
    float x2 = bf2f(qkv[base + d + 64]);
    float c1 = cosb[s * D_ + d];
    float s1 = sinb[s * D_ + d];
    float c2 = cosb[s * D_ + d + 64];
    float s2 = sinb[s * D_ + d + 64];
    qkv[base + d]      = f2bf(x1 * c1 - x2 * s1);
    qkv[base + d + 64] = f2bf(x2 * c2 + x1 * s2);
}

// ---------------- Flash-style MFMA attention (V transposed in LDS) ----------------
__global__ __launch_bounds__(256)
void attn_mfma(const unsigned short* __restrict__ qkv,
               unsigned short* __restrict__ attn)
{
    __shared__ unsigned short Kl[CH * 136];
    __shared__ unsigned short Vt[128 * VSTR];    // [dim][row] transposed
    __shared__ unsigned short Pl[4][16 * 40];

    const int tid  = threadIdx.x;
    const int wave = tid >> 6, lane = tid & 63;
    const int lm   = lane & 15, quad = lane >> 4;
    const int h    = blockIdx.y;
    const int b    = blockIdx.z;
    const int kvh  = h >> 2;
    const int r0b  = blockIdx.x * 64;
    const int rw0  = r0b + wave * 16;

    const size_t qkv_b = (size_t)b * S_ * QKV_OUT;
    const float SCL = 0.12751974f;   // (1/sqrt(128)) * log2(e)

    bf16x8 qf[4];
    {
        const unsigned short* qrow = qkv + qkv_b + (size_t)(rw0 + lm) * QKV_OUT + h * D_ + quad * 8;
        #pragma unroll
        for (int kb = 0; kb < 4; ++kb)
            qf[kb] = *(const bf16x8*)(qrow + kb * 32);
    }

    f32x4 O[8] = {};
    float mrow[4] = {-1e30f, -1e30f, -1e30f, -1e30f};
    float lrow[4] = {0.f, 0.f, 0.f, 0.f};

    const int c0   = max(0, r0b - (WINDOW - 1)) & ~(CH - 1);
    const int cend = r0b + 64 - CH;

    for (int c = c0; c <= cend; c += CH) {
        __syncthreads();
        // K: rows c..c+31, coalesced 16B/lane, padded-136 LDS (conflict-light frag reads)
        #pragma unroll
        for (int p = 0; p < 2; ++p) {
            int idx = tid + p * 256;
            int row = idx >> 4;
            int d0  = (idx & 15) * 8;
            *(u16x8*)&Kl[row * 136 + d0] =
                *(const u16x8*)(qkv + qkv_b + (size_t)(c + row) * QKV_OUT + HID + kvh * D_ + d0);
        }
        // V transposed: thread = 2 rows x 8 dims, packed ds_write_b32 (conflict-free pattern)
        {
            int r2 = (tid & 15) * 2;
            int d0 = (tid >> 4) * 8;
            const unsigned short* vg = qkv + qkv_b + (size_t)(c + r2) * QKV_OUT + HID + NKV * D_ + kvh * D_ + d0;
            u16x8 va = *(const u16x8*)vg;
            u16x8 vb = *(const u16x8*)(vg + QKV_OUT);
            #pragma unroll
            for (int e = 0; e < 8; ++e) {
                unsigned int pack = (unsigned int)va[e] | ((unsigned int)vb[e] << 16);
                *(unsigned int*)&Vt[(d0 + e) * VSTR + r2] = pack;
            }
        }
        __syncthreads();

        if (c + CH - 1 < rw0 - (WINDOW - 1) || c > rw0 + 15) continue;

        // QK^T: two 16-col tiles
        f32x4 s0 = {}, s1 = {};
        #pragma unroll
        for (int kb = 0; kb < 4; ++kb) {
            bf16x8 b0 = *(const bf16x8*)&Kl[lm * 136 + kb * 32 + quad * 8];
            bf16x8 b1 = *(const bf16x8*)&Kl[(16 + lm) * 136 + kb * 32 + quad * 8];
            s0 = __builtin_amdgcn_mfma_f32_16x16x32_bf16(qf[kb], b0, s0, 0, 0, 0);
            s1 = __builtin_amdgcn_mfma_f32_16x16x32_bf16(qf[kb], b1, s1, 0, 0, 0);
        }

        const int j0 = c + lm, j1 = c + 16 + lm;
        float alpha[4];
        #pragma unroll
        for (int r = 0; r < 4; ++r) {
            int row = rw0 + quad * 4 + r;
            float t0 = (j0 <= row && row - j0 < WINDOW) ? s0[r] : -3.0e38f;
            float t1 = (j1 <= row && row - j1 < WINDOW) ? s1[r] : -3.0e38f;
            float cm = fmaxf(t0, t1);
            #pragma unroll
            for (int o = 8; o >= 1; o >>= 1) cm = fmaxf(cm, __shfl_xor(cm, o, 16));
            float mnew = fmaxf(mrow[r], cm);
            float al   = exp2f((mrow[r] - mnew) * SCL);
            float p0   = exp2f((t0 - mnew) * SCL);
            float p1   = exp2f((t1 - mnew) * SCL);
            float rs   = p0 + p1;
            #pragma unroll
            for (int o = 8; o >= 1; o >>= 1) rs += __shfl_xor(rs, o, 16);
            mrow[r] = mnew;
            lrow[r] = lrow[r] * al + rs;
            alpha[r] = al;
            Pl[wave][(quad * 4 + r) * 40 + lm]      = f2bf(p0);
            Pl[wave][(quad * 4 + r) * 40 + 16 + lm] = f2bf(p1);
        }

        #pragma unroll
        for (int nt = 0; nt < 8; ++nt)
            #pragma unroll
            for (int r = 0; r < 4; ++r)
                O[nt][r] *= alpha[r];

        // PV: A = P (wave-private LDS), B = transposed V via ds_read_b128
        bf16x8 pa = *(const bf16x8*)&Pl[wave][lm * 40 + quad * 8];
        #pragma unroll
        for (int nt = 0; nt < 8; ++nt) {
            bf16x8 vbf = *(const bf16x8*)&Vt[(nt * 16 + lm) * VSTR + quad * 8];
            O[nt] = __builtin_amdgcn_mfma_f32_16x16x32_bf16(pa, vbf, O[nt], 0, 0, 0);
        }
    }

    float il[4];
    #pragma unroll
    for (int r = 0; r < 4; ++r) il[r] = 1.0f / lrow[r];
    #pragma unroll
    for (int nt = 0; nt < 8; ++nt)
        #pragma unroll
        for (int r = 0; r < 4; ++r) {
            int row = rw0 + quad * 4 + r;
            attn[(size_t)(b * S_ + row) * (NH * D_) + h * D_ + nt * 16 + lm] = f2bf(O[nt][r] * il[r]);
        }
}

extern "C" void kernel_launch(void* const* d_in, const int* in_sizes, int n_in,
                              void* d_out, int out_size, void* d_ws, size_t ws_size,
                              hipStream_t stream)
{
    const float* hidden = (const float*)d_in[0];
    const float* cosb   = (const float*)d_in[1];
    const float* sinb   = (const float*)d_in[2];
    const float* w_qkv  = (const float*)d_in[3];
    const float* b_qkv  = (const float*)d_in[4];
    const float* w_o    = (const float*)d_in[5];
    const float* b_o    = (const float*)d_in[6];
    float* out = (float*)d_out;

    unsigned char* ws = (unsigned char*)d_ws;
    const size_t QKV_B  = (size_t)M_TOT * QKV_OUT * 2;       // 25.2 MB
    const size_t ATTN_B = (size_t)M_TOT * HID * 2;           // 16.8 MB
    const size_t HB_B   = (size_t)M_TOT * HID * 2;           // 16.8 MB
    const size_t WQ_B   = (size_t)QKV_OUT * HID * 2;         // 50.3 MB
    const size_t WO_B   = (size_t)HID * HID * 2;             // 33.6 MB
    const size_t NEED   = QKV_B + ATTN_B + HB_B + WQ_B;      // wo aliases hb+wq region

    unsigned short* qkv_ws  = (unsigned short*)(ws);
    unsigned short* attn_ws = (unsigned short*)(ws + QKV_B);

    dim3 blk(256);

    if (ws_size >= NEED && WO_B <= HB_B + WQ_B) {
        unsigned short* hb = (unsigned short*)(ws + QKV_B + ATTN_B);
        unsigned short* wq = (unsigned short*)(ws + QKV_B + ATTN_B + HB_B);
        unsigned short* wo = (unsigned short*)(ws + QKV_B + ATTN_B);   // reuse after gemm1

        int n8h = M_TOT * HID / 8;
        int n8q = QKV_OUT * HID / 8;
        int n8o = HID * HID / 8;
        conv_f32_bf16<<<dim3((n8h + 255) / 256), blk, 0, stream>>>(hidden, hb, n8h);
        conv_f32_bf16<<<dim3((n8q + 255) / 256), blk, 0, stream>>>(w_qkv, wq, n8q);
        gemm256_8ph<3, true><<<dim3(QKV_OUT / 192, M_TOT / 256), dim3(512), 0, stream>>>(
            hb, wq, b_qkv, qkv_ws, M_TOT, QKV_OUT, HID);
        rope_kernel<<<dim3((M_TOT * 40 * 64) / 256), blk, 0, stream>>>(qkv_ws, cosb, sinb);
        conv_f32_bf16<<<dim3((n8o + 255) / 256), blk, 0, stream>>>(w_o, wo, n8o);
        attn_mfma<<<dim3(S_ / 64, NH, B_), blk, 0, stream>>>(qkv_ws, attn_ws);
        gemm256_8ph<2, false><<<dim3(HID / 128, M_TOT / 256), dim3(512), 0, stream>>>(
            attn_ws, wo, b_o, out, M_TOT, HID, NH * D_);
    } else {
        gemm_bt_bias<false, true><<<dim3(QKV_OUT / 128, M_TOT / 128), blk, 0, stream>>>(
            hidden, w_qkv, b_qkv, qkv_ws, M_TOT, QKV_OUT, HID);
        rope_kernel<<<dim3((M_TOT * 40 * 64) / 256), blk, 0, stream>>>(qkv_ws, cosb, sinb);
        attn_mfma<<<dim3(S_ / 64, NH, B_), blk, 0, stream>>>(qkv_ws, attn_ws);
        gemm_bt_bias<true, false><<<dim3(HID / 128, M_TOT / 128), blk, 0, stream>>>(
            attn_ws, w_o, b_o, out, M_TOT, HID, NH * D_);
    }
}